// Round 1
// baseline (374.103 us; speedup 1.0000x reference)
//
#include <hip/hip_runtime.h>
#include <math.h>

#define NN 5000
#define NE 160000
#define NF 16

// ws layout (bytes):
// [0,      20480)  deg -> inv_sqrt (5000 f32, padded)
// [20480,  340480) h1 = x@W1      (80000 f32)
// [340480, 660480) g1 = adj@h1
// [660480, 980480) a1 = relu(g1+b1)
// [980480, 1300480) g2 = adj@a1

__global__ void k_deg(const int* __restrict__ dst, float* __restrict__ deg) {
  int t = blockIdx.x * 256 + threadIdx.x;
  if (t < NE) atomicAdd(&deg[dst[t]], 1.0f);
}

__global__ void k_inv(float* __restrict__ deg) {
  int v = blockIdx.x * 256 + threadIdx.x;
  if (v < NN) deg[v] = rsqrtf(deg[v] + 1.0f);  // +1 self loop; deg>=1 always
}

// h1[i][j] += sum_k x[i][k] * W1[k][j]   (k split 5 ways, atomic combine)
// block = 256 threads = 16 rows x 16 cols; W1 line reused x16 rows via L1.
__global__ void k_gemm1(const float* __restrict__ x, const float* __restrict__ w1,
                        float* __restrict__ h1) {
  const int j = threadIdx.x & 15;
  const int i = blockIdx.x * 16 + (threadIdx.x >> 4);
  if (i >= NN) return;
  const int k0 = blockIdx.y * 1000;
  const float* __restrict__ xr = x + (size_t)i * NN + k0;
  const float* __restrict__ wp = w1 + (size_t)k0 * NF + j;
  float a0 = 0.f, a1 = 0.f, a2 = 0.f, a3 = 0.f;
#pragma unroll 2
  for (int k = 0; k < 1000; k += 4) {
    a0 = fmaf(xr[k + 0], wp[(k + 0) * NF], a0);
    a1 = fmaf(xr[k + 1], wp[(k + 1) * NF], a1);
    a2 = fmaf(xr[k + 2], wp[(k + 2) * NF], a2);
    a3 = fmaf(xr[k + 3], wp[(k + 3) * NF], a3);
  }
  atomicAdd(&h1[i * NF + j], (a0 + a1) + (a2 + a3));
}

// self-loop term: g[v][j] = inv[v]^2 * h[v][j]
__global__ void k_self(const float* __restrict__ h1, const float* __restrict__ inv,
                       float* __restrict__ g1) {
  int t = blockIdx.x * 256 + threadIdx.x;
  if (t >= NN * NF) return;
  float iv = inv[t >> 4];
  g1[t] = iv * iv * h1[t];
}

// edge scatter: g[dst][j] += inv[src]*inv[dst] * h[src][j]  (16 threads/edge)
__global__ void k_edge(const int* __restrict__ src, const int* __restrict__ dst,
                       const float* __restrict__ inv, const float* __restrict__ hin,
                       float* __restrict__ gout) {
  int t = blockIdx.x * 256 + threadIdx.x;  // NE*16 = 2,560,000 = 10000*256 exact
  int e = t >> 4, j = t & 15;
  int s = src[e], d = dst[e];
  float c = inv[s] * inv[d];
  atomicAdd(&gout[d * NF + j], c * hin[s * NF + j]);
}

// a1 = relu(g1 + b1); also seed layer-2 self-loop: g2 = inv^2 * a1
__global__ void k_relu2(const float* __restrict__ g1, const float* __restrict__ b1,
                        const float* __restrict__ inv, float* __restrict__ a1,
                        float* __restrict__ g2) {
  int t = blockIdx.x * 256 + threadIdx.x;
  if (t >= NN * NF) return;
  int v = t >> 4, j = t & 15;
  float a = fmaxf(g1[t] + b1[j], 0.f);
  a1[t] = a;
  float iv = inv[v];
  g2[t] = iv * iv * a;
}

// out[row] = log_softmax(g2[row] @ W2 + b2), 4 rows per block, z staged in LDS.
__global__ __launch_bounds__(512) void k_final(const float* __restrict__ g2,
                                               const float* __restrict__ w2,
                                               const float* __restrict__ b2,
                                               float* __restrict__ out) {
  __shared__ float zs[4 * NN];   // 80000 B; +scratch => ~80.5 KB => 2 blocks/CU
  __shared__ float gsh[64];
  __shared__ float red[8 * 4];
  __shared__ float rowmax[4];
  __shared__ float rowoff[4];
  const int tid = threadIdx.x;
  const int lane = tid & 63;
  const int wv = tid >> 6;  // 8 waves
  const int row0 = blockIdx.x * 4;

  if (tid < 64) gsh[tid] = g2[row0 * NF + tid];
  __syncthreads();
  float g[4][NF];
#pragma unroll
  for (int r = 0; r < 4; ++r)
#pragma unroll
    for (int k = 0; k < NF; ++k) g[r][k] = gsh[r * NF + k];

  float mx[4] = {-1e30f, -1e30f, -1e30f, -1e30f};
  for (int jc = tid; jc < NN; jc += 512) {
    float w[NF];
#pragma unroll
    for (int k = 0; k < NF; ++k) w[k] = w2[k * NN + jc];
    const float bb = b2[jc];
#pragma unroll
    for (int r = 0; r < 4; ++r) {
      float z = bb;
#pragma unroll
      for (int k = 0; k < NF; ++k) z = fmaf(g[r][k], w[k], z);
      zs[r * NN + jc] = z;
      mx[r] = fmaxf(mx[r], z);
    }
  }
  // block-level max per row
#pragma unroll
  for (int r = 0; r < 4; ++r) {
    float m = mx[r];
    for (int off = 32; off; off >>= 1) m = fmaxf(m, __shfl_xor(m, off));
    if (lane == 0) red[wv * 4 + r] = m;
  }
  __syncthreads();
  if (tid < 4) {
    float m = red[tid];
#pragma unroll
    for (int w = 1; w < 8; ++w) m = fmaxf(m, red[w * 4 + tid]);
    rowmax[tid] = m;
  }
  __syncthreads();
  const float rm0 = rowmax[0], rm1 = rowmax[1], rm2 = rowmax[2], rm3 = rowmax[3];

  float sm[4] = {0.f, 0.f, 0.f, 0.f};
  for (int jc = tid; jc < NN; jc += 512) {
    sm[0] += __expf(zs[0 * NN + jc] - rm0);
    sm[1] += __expf(zs[1 * NN + jc] - rm1);
    sm[2] += __expf(zs[2 * NN + jc] - rm2);
    sm[3] += __expf(zs[3 * NN + jc] - rm3);
  }
#pragma unroll
  for (int r = 0; r < 4; ++r) {
    float s = sm[r];
    for (int off = 32; off; off >>= 1) s += __shfl_xor(s, off);
    if (lane == 0) red[wv * 4 + r] = s;
  }
  __syncthreads();
  if (tid < 4) {
    float s = red[tid];
#pragma unroll
    for (int w = 1; w < 8; ++w) s += red[w * 4 + tid];
    rowoff[tid] = rowmax[tid] + logf(s);
  }
  __syncthreads();
  const float o0 = rowoff[0], o1 = rowoff[1], o2 = rowoff[2], o3 = rowoff[3];
  for (int jc = tid; jc < NN; jc += 512) {
    out[(size_t)(row0 + 0) * NN + jc] = zs[0 * NN + jc] - o0;
    out[(size_t)(row0 + 1) * NN + jc] = zs[1 * NN + jc] - o1;
    out[(size_t)(row0 + 2) * NN + jc] = zs[2 * NN + jc] - o2;
    out[(size_t)(row0 + 3) * NN + jc] = zs[3 * NN + jc] - o3;
  }
}

extern "C" void kernel_launch(void* const* d_in, const int* in_sizes, int n_in,
                              void* d_out, int out_size, void* d_ws, size_t ws_size,
                              hipStream_t stream) {
  const float* x  = (const float*)d_in[0];
  const int*   src = (const int*)d_in[1];
  const int*   dst = (const int*)d_in[2];
  const float* W1 = (const float*)d_in[3];
  const float* b1 = (const float*)d_in[4];
  const float* W2 = (const float*)d_in[5];
  const float* b2 = (const float*)d_in[6];
  float* out = (float*)d_out;

  char* ws = (char*)d_ws;
  float* deg = (float*)(ws);            // becomes inv_sqrt after k_inv
  float* h1  = (float*)(ws + 20480);
  float* g1  = (float*)(ws + 340480);
  float* a1  = (float*)(ws + 660480);
  float* g2  = (float*)(ws + 980480);

  // zero deg + h1 (ws is poisoned 0xAA before every timed launch)
  hipMemsetAsync(d_ws, 0, 340480, stream);
  k_deg<<<(NE + 255) / 256, 256, 0, stream>>>(dst, deg);
  k_inv<<<(NN + 255) / 256, 256, 0, stream>>>(deg);
  k_gemm1<<<dim3(313, 5), 256, 0, stream>>>(x, W1, h1);
  k_self<<<(NN * NF + 255) / 256, 256, 0, stream>>>(h1, deg, g1);
  k_edge<<<(NE * NF) / 256, 256, 0, stream>>>(src, dst, deg, h1, g1);
  k_relu2<<<(NN * NF + 255) / 256, 256, 0, stream>>>(g1, b1, deg, a1, g2);
  k_edge<<<(NE * NF) / 256, 256, 0, stream>>>(src, dst, deg, a1, g2);
  k_final<<<NN / 4, 512, 0, stream>>>(g2, W2, b2, out);
}

// Round 2
// 338.455 us; speedup vs baseline: 1.1053x; 1.1053x over previous
//
#include <hip/hip_runtime.h>
#include <math.h>

#define NN 5000
#define NE 160000
#define NF 16

// ws layout (bytes):
// [0,      20480)  deg -> inv_sqrt (5000 f32, padded)
// [20480,  340480) h1 = x@W1      (80000 f32)
// [340480, 660480) g1 = adj@h1
// [660480, 980480) a1 = relu(g1+b1)
// [980480, 1300480) g2 = adj@a1

__global__ void k_deg(const int* __restrict__ dst, float* __restrict__ deg) {
  int t = blockIdx.x * 256 + threadIdx.x;
  if (t < NE) atomicAdd(&deg[dst[t]], 1.0f);
}

__global__ void k_inv(float* __restrict__ deg) {
  int v = blockIdx.x * 256 + threadIdx.x;
  if (v < NN) deg[v] = rsqrtf(deg[v] + 1.0f);  // +1 self loop; deg>=1 always
}

// h1 = x @ W1. Wave-per-row, split-k x2 (blockIdx.y).
// lane = (u = lane>>2 [k-class 0..15], q = lane&3 [j-quad]).
// Per superiter (64 k): lane loads x[i][kb..kb+3] (float4, q-broadcast) and
// W1 rows kb..kb+3, quad q (4x dwordx4, 4 lanes/line -> dense 1KB/instr).
// Reduce over u via shfl_xor(4,8,16,32); lanes 0..3 atomicAdd float4-worth.
__global__ __launch_bounds__(256) void k_gemm1(const float* __restrict__ x,
                                               const float* __restrict__ w1,
                                               float* __restrict__ h1) {
  const int lane = threadIdx.x & 63;
  const int wv = threadIdx.x >> 6;
  const int i = blockIdx.x * 4 + wv;     // row 0..4999 (grid.x = 1250)
  const int u = lane >> 2;
  const int q = lane & 3;
  const int koff = blockIdx.y * 2500;    // split-k halves [0,2500) [2500,5000)
  const int kend = koff + 2500;
  const float* __restrict__ xr = x + (size_t)i * NN;

  float ax = 0.f, ay = 0.f, az = 0.f, aw = 0.f;
#pragma unroll 2
  for (int s = 0; s < 40; ++s) {
    const int kb = koff + s * 64 + u * 4;
    if (kb < kend) {
      const float4 xv = *(const float4*)(xr + kb);
      const float* __restrict__ wb = w1 + (size_t)kb * NF + q * 4;
      const float4 w0 = *(const float4*)(wb);
      const float4 w1v = *(const float4*)(wb + NF);
      const float4 w2v = *(const float4*)(wb + 2 * NF);
      const float4 w3v = *(const float4*)(wb + 3 * NF);
      ax = fmaf(xv.x, w0.x, ax); ay = fmaf(xv.x, w0.y, ay);
      az = fmaf(xv.x, w0.z, az); aw = fmaf(xv.x, w0.w, aw);
      ax = fmaf(xv.y, w1v.x, ax); ay = fmaf(xv.y, w1v.y, ay);
      az = fmaf(xv.y, w1v.z, az); aw = fmaf(xv.y, w1v.w, aw);
      ax = fmaf(xv.z, w2v.x, ax); ay = fmaf(xv.z, w2v.y, ay);
      az = fmaf(xv.z, w2v.z, az); aw = fmaf(xv.z, w2v.w, aw);
      ax = fmaf(xv.w, w3v.x, ax); ay = fmaf(xv.w, w3v.y, ay);
      az = fmaf(xv.w, w3v.z, az); aw = fmaf(xv.w, w3v.w, aw);
    }
  }
#pragma unroll
  for (int off = 4; off <= 32; off <<= 1) {
    ax += __shfl_xor(ax, off);
    ay += __shfl_xor(ay, off);
    az += __shfl_xor(az, off);
    aw += __shfl_xor(aw, off);
  }
  if (lane < 4) {  // lane==q here; j base = q*4
    float* p = h1 + i * NF + q * 4;
    atomicAdd(p + 0, ax);
    atomicAdd(p + 1, ay);
    atomicAdd(p + 2, az);
    atomicAdd(p + 3, aw);
  }
}

// self-loop term: g[v][j] = inv[v]^2 * h[v][j]
__global__ void k_self(const float* __restrict__ h1, const float* __restrict__ inv,
                       float* __restrict__ g1) {
  int t = blockIdx.x * 256 + threadIdx.x;
  if (t >= NN * NF) return;
  float iv = inv[t >> 4];
  g1[t] = iv * iv * h1[t];
}

// edge scatter: g[dst][j] += inv[src]*inv[dst] * h[src][j]  (16 threads/edge)
__global__ void k_edge(const int* __restrict__ src, const int* __restrict__ dst,
                       const float* __restrict__ inv, const float* __restrict__ hin,
                       float* __restrict__ gout) {
  int t = blockIdx.x * 256 + threadIdx.x;  // NE*16 = 2,560,000 = 10000*256 exact
  int e = t >> 4, j = t & 15;
  int s = src[e], d = dst[e];
  float c = inv[s] * inv[d];
  atomicAdd(&gout[d * NF + j], c * hin[s * NF + j]);
}

// a1 = relu(g1 + b1); also seed layer-2 self-loop: g2 = inv^2 * a1
__global__ void k_relu2(const float* __restrict__ g1, const float* __restrict__ b1,
                        const float* __restrict__ inv, float* __restrict__ a1,
                        float* __restrict__ g2) {
  int t = blockIdx.x * 256 + threadIdx.x;
  if (t >= NN * NF) return;
  int v = t >> 4, j = t & 15;
  float a = fmaxf(g1[t] + b1[j], 0.f);
  a1[t] = a;
  float iv = inv[v];
  g2[t] = iv * iv * a;
}

// out[row] = log_softmax(g2[row] @ W2 + b2), 4 rows per block, z staged in LDS.
__global__ __launch_bounds__(512) void k_final(const float* __restrict__ g2,
                                               const float* __restrict__ w2,
                                               const float* __restrict__ b2,
                                               float* __restrict__ out) {
  __shared__ float zs[4 * NN];   // 80000 B
  __shared__ float gsh[64];
  __shared__ float red[8 * 4];
  __shared__ float rowmax[4];
  __shared__ float rowoff[4];
  const int tid = threadIdx.x;
  const int lane = tid & 63;
  const int wv = tid >> 6;  // 8 waves
  const int row0 = blockIdx.x * 4;

  if (tid < 64) gsh[tid] = g2[row0 * NF + tid];
  __syncthreads();
  float g[4][NF];
#pragma unroll
  for (int r = 0; r < 4; ++r)
#pragma unroll
    for (int k = 0; k < NF; ++k) g[r][k] = gsh[r * NF + k];

  float mx[4] = {-1e30f, -1e30f, -1e30f, -1e30f};
  for (int jc = tid; jc < NN; jc += 512) {
    float w[NF];
#pragma unroll
    for (int k = 0; k < NF; ++k) w[k] = w2[k * NN + jc];
    const float bb = b2[jc];
#pragma unroll
    for (int r = 0; r < 4; ++r) {
      float z = bb;
#pragma unroll
      for (int k = 0; k < NF; ++k) z = fmaf(g[r][k], w[k], z);
      zs[r * NN + jc] = z;
      mx[r] = fmaxf(mx[r], z);
    }
  }
#pragma unroll
  for (int r = 0; r < 4; ++r) {
    float m = mx[r];
    for (int off = 32; off; off >>= 1) m = fmaxf(m, __shfl_xor(m, off));
    if (lane == 0) red[wv * 4 + r] = m;
  }
  __syncthreads();
  if (tid < 4) {
    float m = red[tid];
#pragma unroll
    for (int w = 1; w < 8; ++w) m = fmaxf(m, red[w * 4 + tid]);
    rowmax[tid] = m;
  }
  __syncthreads();
  const float rm0 = rowmax[0], rm1 = rowmax[1], rm2 = rowmax[2], rm3 = rowmax[3];

  float sm[4] = {0.f, 0.f, 0.f, 0.f};
  for (int jc = tid; jc < NN; jc += 512) {
    sm[0] += __expf(zs[0 * NN + jc] - rm0);
    sm[1] += __expf(zs[1 * NN + jc] - rm1);
    sm[2] += __expf(zs[2 * NN + jc] - rm2);
    sm[3] += __expf(zs[3 * NN + jc] - rm3);
  }
#pragma unroll
  for (int r = 0; r < 4; ++r) {
    float s = sm[r];
    for (int off = 32; off; off >>= 1) s += __shfl_xor(s, off);
    if (lane == 0) red[wv * 4 + r] = s;
  }
  __syncthreads();
  if (tid < 4) {
    float s = red[tid];
#pragma unroll
    for (int w = 1; w < 8; ++w) s += red[w * 4 + tid];
    rowoff[tid] = rowmax[tid] + logf(s);
  }
  __syncthreads();
  const float o0 = rowoff[0], o1 = rowoff[1], o2 = rowoff[2], o3 = rowoff[3];
  for (int jc = tid; jc < NN; jc += 512) {
    out[(size_t)(row0 + 0) * NN + jc] = zs[0 * NN + jc] - o0;
    out[(size_t)(row0 + 1) * NN + jc] = zs[1 * NN + jc] - o1;
    out[(size_t)(row0 + 2) * NN + jc] = zs[2 * NN + jc] - o2;
    out[(size_t)(row0 + 3) * NN + jc] = zs[3 * NN + jc] - o3;
  }
}

extern "C" void kernel_launch(void* const* d_in, const int* in_sizes, int n_in,
                              void* d_out, int out_size, void* d_ws, size_t ws_size,
                              hipStream_t stream) {
  const float* x  = (const float*)d_in[0];
  const int*   src = (const int*)d_in[1];
  const int*   dst = (const int*)d_in[2];
  const float* W1 = (const float*)d_in[3];
  const float* b1 = (const float*)d_in[4];
  const float* W2 = (const float*)d_in[5];
  const float* b2 = (const float*)d_in[6];
  float* out = (float*)d_out;

  char* ws = (char*)d_ws;
  float* deg = (float*)(ws);            // becomes inv_sqrt after k_inv
  float* h1  = (float*)(ws + 20480);
  float* g1  = (float*)(ws + 340480);
  float* a1  = (float*)(ws + 660480);
  float* g2  = (float*)(ws + 980480);

  // zero deg + h1 (split-k atomics accumulate into h1)
  hipMemsetAsync(d_ws, 0, 340480, stream);
  k_deg<<<(NE + 255) / 256, 256, 0, stream>>>(dst, deg);
  k_inv<<<(NN + 255) / 256, 256, 0, stream>>>(deg);
  k_gemm1<<<dim3(1250, 2), 256, 0, stream>>>(x, W1, h1);
  k_self<<<(NN * NF + 255) / 256, 256, 0, stream>>>(h1, deg, g1);
  k_edge<<<(NE * NF) / 256, 256, 0, stream>>>(src, dst, deg, h1, g1);
  k_relu2<<<(NN * NF + 255) / 256, 256, 0, stream>>>(g1, b1, deg, a1, g2);
  k_edge<<<(NE * NF) / 256, 256, 0, stream>>>(src, dst, deg, a1, g2);
  k_final<<<NN / 4, 512, 0, stream>>>(g2, W2, b2, out);
}

// Round 4
// 286.491 us; speedup vs baseline: 1.3058x; 1.1814x over previous
//
#include <hip/hip_runtime.h>
#include <math.h>

#define NN 5000
#define NE 160000
#define NF 16
#define CK 256

// ws layout (bytes):
// [0,      20480)  deg -> inv_sqrt (5000 f32, padded)
// [20480,  340480) h1 = x@W1      (80000 f32)
// [340480, 660480) g1 = adj@h1
// [660480, 980480) a1 = relu(g1+b1)
// [980480, 1300480) g2 = adj@a1

__global__ void k_deg(const int* __restrict__ dst, float* __restrict__ deg) {
  int t = blockIdx.x * 256 + threadIdx.x;
  if (t < NE) atomicAdd(&deg[dst[t]], 1.0f);
}

__global__ void k_inv(float* __restrict__ deg) {
  int v = blockIdx.x * 256 + threadIdx.x;
  if (v < NN) deg[v] = rsqrtf(deg[v] + 1.0f);  // +1 self loop; deg>=1 always
}

// h1 = x @ W1, LDS-tiled. Block = 256 thr = 4 waves, 16 rows, k-chunk 256.
// Stage x-tile[16][256] + w1-tile[256][16] in LDS (32 KB -> 5 blocks/CU).
// Lane = (kk=lane>>2 in [0,16), jq=lane&3): per c-step (k = c*16+kk):
//   1x ds_read_b128 W1[k][jq*4..+4] + 4x broadcast ds_read_b32 x[r][k],
//   16 FMA into acc[r][jj].
// Epilogue: rotating butterfly over kk-lanes -> 1 atomicAdd per lane.
// NOTE: butterfly must iterate m = 32,16,8,4 (high bit first) so that the
// surviving idx at lane kk equals kk (m=4-first gives bitrev(kk) -- R3 bug).
__global__ __launch_bounds__(256) void k_gemm1(const float* __restrict__ x,
                                               const float* __restrict__ w1,
                                               float* __restrict__ h1) {
  __shared__ float xs[16 * CK];   // [r_local][k_local]
  __shared__ float ws[CK * NF];   // [k_local][j]
  const int tid = threadIdx.x;
  const int lane = tid & 63;
  const int wv = tid >> 6;
  const int kk = lane >> 2;
  const int jq = lane & 3;
  const int rowbase = blockIdx.x * 16;
  const int kbeg = blockIdx.y * 1252;               // 1252 % 4 == 0
  const int kend = (kbeg + 1252 < NN) ? kbeg + 1252 : NN;

  float acc[16];
#pragma unroll
  for (int i = 0; i < 16; ++i) acc[i] = 0.f;

  const int srow = tid >> 4;   // staging row 0..15
  const int sf4 = tid & 15;    // staging float4 slot
  const int grow = rowbase + srow;
  const float* __restrict__ xrow = x + (size_t)grow * NN;

  for (int kc = kbeg; kc < kend; kc += CK) {
    __syncthreads();
    // stage x: 4 float4 per thread (dense 1KB/row coalesced)
#pragma unroll
    for (int p = 0; p < 4; ++p) {
      const int s4 = sf4 + 16 * p;     // float4 slot 0..63
      const int col = kc + s4 * 4;
      float4 v = make_float4(0.f, 0.f, 0.f, 0.f);
      if (grow < NN && col + 4 <= kend) v = *(const float4*)(xrow + col);
      *(float4*)(&xs[srow * CK + s4 * 4]) = v;
    }
    // stage w1: thread t -> k row kc+t (16 floats)
    {
      const int k = kc + tid;
      if (k < kend) {
        const float4* __restrict__ wr = (const float4*)(w1 + (size_t)k * NF);
#pragma unroll
        for (int q = 0; q < 4; ++q) *(float4*)(&ws[tid * NF + q * 4]) = wr[q];
      } else {
#pragma unroll
        for (int q = 0; q < 4; ++q)
          *(float4*)(&ws[tid * NF + q * 4]) = make_float4(0.f, 0.f, 0.f, 0.f);
      }
    }
    __syncthreads();
    // compute
    const float* __restrict__ xb = &xs[(wv * 4) * CK + kk];
    const float* __restrict__ wb = &ws[kk * NF + jq * 4];
#pragma unroll
    for (int c = 0; c < 16; ++c) {
      const float4 w4 = *(const float4*)(wb + c * (16 * NF));
      const float x0 = xb[0 * CK + c * 16];
      const float x1 = xb[1 * CK + c * 16];
      const float x2 = xb[2 * CK + c * 16];
      const float x3 = xb[3 * CK + c * 16];
      acc[0] = fmaf(x0, w4.x, acc[0]);  acc[1] = fmaf(x0, w4.y, acc[1]);
      acc[2] = fmaf(x0, w4.z, acc[2]);  acc[3] = fmaf(x0, w4.w, acc[3]);
      acc[4] = fmaf(x1, w4.x, acc[4]);  acc[5] = fmaf(x1, w4.y, acc[5]);
      acc[6] = fmaf(x1, w4.z, acc[6]);  acc[7] = fmaf(x1, w4.w, acc[7]);
      acc[8] = fmaf(x2, w4.x, acc[8]);  acc[9] = fmaf(x2, w4.y, acc[9]);
      acc[10] = fmaf(x2, w4.z, acc[10]); acc[11] = fmaf(x2, w4.w, acc[11]);
      acc[12] = fmaf(x3, w4.x, acc[12]); acc[13] = fmaf(x3, w4.y, acc[13]);
      acc[14] = fmaf(x3, w4.z, acc[14]); acc[15] = fmaf(x3, w4.w, acc[15]);
    }
  }

  // Rotating butterfly over kk lanes, HIGH bit first: at step with mask m
  // (kk bit b), the surviving idx half is idx bit (3-step), so iterating
  // m = 32,16,8,4 aligns idx bit b <- kk bit b. After: lane holds idx == kk.
  int len = 16;
#pragma unroll
  for (int m = 32; m >= 4; m >>= 1) {
    len >>= 1;
    const bool hi = (lane & m) != 0;
#pragma unroll
    for (int i = 0; i < len; ++i) {
      float keep = hi ? acc[i + len] : acc[i];
      float give = hi ? acc[i] : acc[i + len];
      acc[i] = keep + __shfl_xor(give, m);
    }
  }
  const int r = kk >> 2, jj = kk & 3;
  const int row = rowbase + wv * 4 + r;
  if (row < NN) atomicAdd(&h1[row * NF + jq * 4 + jj], acc[0]);
}

// self-loop term: g[v][j] = inv[v]^2 * h[v][j]
__global__ void k_self(const float* __restrict__ h1, const float* __restrict__ inv,
                       float* __restrict__ g1) {
  int t = blockIdx.x * 256 + threadIdx.x;
  if (t >= NN * NF) return;
  float iv = inv[t >> 4];
  g1[t] = iv * iv * h1[t];
}

// edge scatter: g[dst][j] += inv[src]*inv[dst] * h[src][j]  (16 threads/edge)
__global__ void k_edge(const int* __restrict__ src, const int* __restrict__ dst,
                       const float* __restrict__ inv, const float* __restrict__ hin,
                       float* __restrict__ gout) {
  int t = blockIdx.x * 256 + threadIdx.x;  // NE*16 = 2,560,000 = 10000*256 exact
  int e = t >> 4, j = t & 15;
  int s = src[e], d = dst[e];
  float c = inv[s] * inv[d];
  atomicAdd(&gout[d * NF + j], c * hin[s * NF + j]);
}

// a1 = relu(g1 + b1); also seed layer-2 self-loop: g2 = inv^2 * a1
__global__ void k_relu2(const float* __restrict__ g1, const float* __restrict__ b1,
                        const float* __restrict__ inv, float* __restrict__ a1,
                        float* __restrict__ g2) {
  int t = blockIdx.x * 256 + threadIdx.x;
  if (t >= NN * NF) return;
  int v = t >> 4, j = t & 15;
  float a = fmaxf(g1[t] + b1[j], 0.f);
  a1[t] = a;
  float iv = inv[v];
  g2[t] = iv * iv * a;
}

// out[row] = log_softmax(g2[row] @ W2 + b2), 4 rows per block, z staged in LDS.
__global__ __launch_bounds__(512) void k_final(const float* __restrict__ g2,
                                               const float* __restrict__ w2,
                                               const float* __restrict__ b2,
                                               float* __restrict__ out) {
  __shared__ float zs[4 * NN];   // 80000 B
  __shared__ float gsh[64];
  __shared__ float red[8 * 4];
  __shared__ float rowmax[4];
  __shared__ float rowoff[4];
  const int tid = threadIdx.x;
  const int lane = tid & 63;
  const int wv = tid >> 6;  // 8 waves
  const int row0 = blockIdx.x * 4;

  if (tid < 64) gsh[tid] = g2[row0 * NF + tid];
  __syncthreads();
  float g[4][NF];
#pragma unroll
  for (int r = 0; r < 4; ++r)
#pragma unroll
    for (int k = 0; k < NF; ++k) g[r][k] = gsh[r * NF + k];

  float mx[4] = {-1e30f, -1e30f, -1e30f, -1e30f};
  for (int jc = tid; jc < NN; jc += 512) {
    float w[NF];
#pragma unroll
    for (int k = 0; k < NF; ++k) w[k] = w2[k * NN + jc];
    const float bb = b2[jc];
#pragma unroll
    for (int r = 0; r < 4; ++r) {
      float z = bb;
#pragma unroll
      for (int k = 0; k < NF; ++k) z = fmaf(g[r][k], w[k], z);
      zs[r * NN + jc] = z;
      mx[r] = fmaxf(mx[r], z);
    }
  }
#pragma unroll
  for (int r = 0; r < 4; ++r) {
    float m = mx[r];
    for (int off = 32; off; off >>= 1) m = fmaxf(m, __shfl_xor(m, off));
    if (lane == 0) red[wv * 4 + r] = m;
  }
  __syncthreads();
  if (tid < 4) {
    float m = red[tid];
#pragma unroll
    for (int w = 1; w < 8; ++w) m = fmaxf(m, red[w * 4 + tid]);
    rowmax[tid] = m;
  }
  __syncthreads();
  const float rm0 = rowmax[0], rm1 = rowmax[1], rm2 = rowmax[2], rm3 = rowmax[3];

  float sm[4] = {0.f, 0.f, 0.f, 0.f};
  for (int jc = tid; jc < NN; jc += 512) {
    sm[0] += __expf(zs[0 * NN + jc] - rm0);
    sm[1] += __expf(zs[1 * NN + jc] - rm1);
    sm[2] += __expf(zs[2 * NN + jc] - rm2);
    sm[3] += __expf(zs[3 * NN + jc] - rm3);
  }
#pragma unroll
  for (int r = 0; r < 4; ++r) {
    float s = sm[r];
    for (int off = 32; off; off >>= 1) s += __shfl_xor(s, off);
    if (lane == 0) red[wv * 4 + r] = s;
  }
  __syncthreads();
  if (tid < 4) {
    float s = red[tid];
#pragma unroll
    for (int w = 1; w < 8; ++w) s += red[w * 4 + tid];
    rowoff[tid] = rowmax[tid] + logf(s);
  }
  __syncthreads();
  const float o0 = rowoff[0], o1 = rowoff[1], o2 = rowoff[2], o3 = rowoff[3];
  for (int jc = tid; jc < NN; jc += 512) {
    out[(size_t)(row0 + 0) * NN + jc] = zs[0 * NN + jc] - o0;
    out[(size_t)(row0 + 1) * NN + jc] = zs[1 * NN + jc] - o1;
    out[(size_t)(row0 + 2) * NN + jc] = zs[2 * NN + jc] - o2;
    out[(size_t)(row0 + 3) * NN + jc] = zs[3 * NN + jc] - o3;
  }
}

extern "C" void kernel_launch(void* const* d_in, const int* in_sizes, int n_in,
                              void* d_out, int out_size, void* d_ws, size_t ws_size,
                              hipStream_t stream) {
  const float* x  = (const float*)d_in[0];
  const int*   src = (const int*)d_in[1];
  const int*   dst = (const int*)d_in[2];
  const float* W1 = (const float*)d_in[3];
  const float* b1 = (const float*)d_in[4];
  const float* W2 = (const float*)d_in[5];
  const float* b2 = (const float*)d_in[6];
  float* out = (float*)d_out;

  char* ws = (char*)d_ws;
  float* deg = (float*)(ws);            // becomes inv_sqrt after k_inv
  float* h1  = (float*)(ws + 20480);
  float* g1  = (float*)(ws + 340480);
  float* a1  = (float*)(ws + 660480);
  float* g2  = (float*)(ws + 980480);

  // zero deg + h1 (split-k atomics accumulate into h1)
  hipMemsetAsync(d_ws, 0, 340480, stream);
  k_deg<<<(NE + 255) / 256, 256, 0, stream>>>(dst, deg);
  k_inv<<<(NN + 255) / 256, 256, 0, stream>>>(deg);
  k_gemm1<<<dim3(313, 4), 256, 0, stream>>>(x, W1, h1);
  k_self<<<(NN * NF + 255) / 256, 256, 0, stream>>>(h1, deg, g1);
  k_edge<<<(NE * NF) / 256, 256, 0, stream>>>(src, dst, deg, h1, g1);
  k_relu2<<<(NN * NF + 255) / 256, 256, 0, stream>>>(g1, b1, deg, a1, g2);
  k_edge<<<(NE * NF) / 256, 256, 0, stream>>>(src, dst, deg, a1, g2);
  k_final<<<NN / 4, 512, 0, stream>>>(g2, W2, b2, out);
}